// Round 6
// baseline (312.796 us; speedup 1.0000x reference)
//
#include <hip/hip_runtime.h>
#include <math.h>

#define NHID 128
#define CHUNK 1024

typedef __attribute__((ext_vector_type(8))) short bf16x8;
typedef __attribute__((ext_vector_type(4))) float f32x4;

union BF8 { ushort u[8]; bf16x8 v; };

__device__ __forceinline__ ushort f2bf(float f) {
    unsigned int u = __float_as_uint(f);
    u += 0x7FFFu + ((u >> 16) & 1u);      // round-to-nearest-even
    return (ushort)(u >> 16);
}
__device__ __forceinline__ float bfh(unsigned int v) { return __uint_as_float(v << 16); }
__device__ __forceinline__ float bfl(unsigned int v) { return __uint_as_float(v & 0xffff0000u); }

// Branch-free GELU (A&S 7.1.26 erf, max err ~1.5e-7)
__device__ __forceinline__ float gelu_fast(float x) {
    float ax = fabsf(x);
    float t  = __builtin_amdgcn_rcpf(fmaf(0.23165493f, ax, 1.0f));
    float p  = t * fmaf(t, fmaf(t, fmaf(t, fmaf(t, 1.061405429f, -1.453152027f),
                                        1.421413741f), -0.284496736f), 0.254829592f);
    float e  = __builtin_amdgcn_exp2f(-0.7213475204f * ax * ax);
    float hax = 0.5f * ax;
    return fmaf(-hax, p * e, 0.5f * x + hax);
}

// ---------------------------------------------------------------------------
// Weight prep: bf16, [col][k] layout so MFMA B-frags are per-lane contiguous 16B.
// ---------------------------------------------------------------------------
__global__ void k_build_wc1t(const float* __restrict__ Wm1, ushort* __restrict__ WC1T) {
    int idx = blockIdx.x * blockDim.x + threadIdx.x;   // 256*320
    int c = idx / 320, k = idx % 320;
    float v;
    if (k < 128) {
        v = (c < 128) ? Wm1[k * 128 + c] : Wm1[(128 + k) * 128 + (c - 128)];
    } else if (k < 256) {
        int kk = k - 128;
        v = (c < 128) ? Wm1[(256 + kk) * 128 + c] : -Wm1[(256 + kk) * 128 + (c - 128)];
    } else {
        int kk = k - 256;
        v = (c < 128) ? 0.0f : Wm1[(384 + kk) * 128 + (c - 128)];
    }
    WC1T[idx] = f2bf(v);
}

__global__ void k_build_wuct(const float* __restrict__ Wu1, const float* __restrict__ Wm2,
                             const float* __restrict__ bm2, ushort* __restrict__ WUCT,
                             float* __restrict__ BV) {
    int idx = blockIdx.x * blockDim.x + threadIdx.x;   // 128*256
    int c = idx >> 8, k = idx & 255;
    float v;
    if (k < 128) {
        v = Wu1[k * 128 + c];
    } else {
        int i = k - 128;
        float acc = 0.f;
        for (int j = 0; j < 128; ++j) acc += Wm2[i * 128 + j] * Wu1[(128 + j) * 128 + c];
        v = acc;
    }
    WUCT[idx] = f2bf(v);
    if (idx < 128) {
        float acc = 0.f;
        for (int j = 0; j < 128; ++j) acc += bm2[j] * Wu1[(128 + j) * 128 + idx];
        BV[idx] = acc;
    }
}

__global__ void k_build_wu2t(const float* __restrict__ Wu2, ushort* __restrict__ WU2T) {
    int idx = blockIdx.x * blockDim.x + threadIdx.x;   // 128*128
    int c = idx >> 7, k = idx & 127;
    WU2T[idx] = f2bf(Wu2[k * 128 + c]);
}

// ---------------------------------------------------------------------------
// Counting sort: zero -> hist -> (chunksum, chunkscan, chunkoffs) -> scatter
// ---------------------------------------------------------------------------
__global__ void k_zero_i(int* __restrict__ p, int n) {
    int i = blockIdx.x * blockDim.x + threadIdx.x;
    if (i < n) p[i] = 0;
}
__global__ void k_hist(const int* __restrict__ dst, int* __restrict__ deg, int E) {
    int i = blockIdx.x * blockDim.x + threadIdx.x;
    if (i < E) atomicAdd(&deg[dst[i]], 1);
}

// per-1024-chunk sums (deg zero-padded to NP)
__global__ __launch_bounds__(256) void k_chunksum(const int* __restrict__ deg,
                                                  int* __restrict__ csum) {
    int c = blockIdx.x, tid = threadIdx.x;
    int4 v = ((const int4*)(deg + (size_t)c * CHUNK))[tid];
    int ts = v.x + v.y + v.z + v.w;
    #pragma unroll
    for (int d = 1; d < 64; d <<= 1) ts += __shfl_xor(ts, d);
    __shared__ int wsum[4];
    if ((tid & 63) == 0) wsum[tid >> 6] = ts;
    __syncthreads();
    if (tid == 0) csum[c] = wsum[0] + wsum[1] + wsum[2] + wsum[3];
}

// single wave: exclusive scan of chunk sums; also offs[N] = E
__global__ void k_chunkscan(const int* __restrict__ csum, int* __restrict__ cbase,
                            int C, int* __restrict__ offs, int N, int E) {
    int lane = threadIdx.x;   // 64
    int carry = 0;
    for (int b = 0; b < C; b += 64) {
        int v = (b + lane < C) ? csum[b + lane] : 0;
        int incl = v;
        #pragma unroll
        for (int d = 1; d < 64; d <<= 1) {
            int t = __shfl_up(incl, d);
            if (lane >= d) incl += t;
        }
        if (b + lane < C) cbase[b + lane] = carry + incl - v;
        carry += __shfl(incl, 63);
    }
    if (lane == 0) offs[N] = E;
}

// per-chunk scan + chunk base -> offs, cursor
__global__ __launch_bounds__(256) void k_chunkoffs(const int* __restrict__ deg,
                                                   const int* __restrict__ cbase,
                                                   int* __restrict__ offs,
                                                   int* __restrict__ cursor) {
    int c = blockIdx.x, tid = threadIdx.x;
    int lane = tid & 63, wid = tid >> 6;
    int4 v = ((const int4*)(deg + (size_t)c * CHUNK))[tid];
    int t0 = v.x, t1 = t0 + v.y, t2 = t1 + v.z, ts = t2 + v.w;
    int incl = ts;
    #pragma unroll
    for (int d = 1; d < 64; d <<= 1) {
        int t = __shfl_up(incl, d);
        if (lane >= d) incl += t;
    }
    __shared__ int wz[4];
    if (lane == 63) wz[wid] = incl;
    __syncthreads();
    int wbase = 0;
    for (int k2 = 0; k2 < wid; ++k2) wbase += wz[k2];
    int eb = cbase[c] + wbase + incl - ts;
    int4 o = make_int4(eb, eb + t0, eb + t1, eb + t2);
    ((int4*)(offs + (size_t)c * CHUNK))[tid] = o;
    ((int4*)(cursor + (size_t)c * CHUNK))[tid] = o;
}

__global__ void k_scatter(const int* __restrict__ src, const int* __restrict__ dst,
                          const float* __restrict__ w, int* __restrict__ cursor,
                          int2* __restrict__ rec, int E) {
    int i = blockIdx.x * blockDim.x + threadIdx.x;
    if (i < E) {
        int d = dst[i];
        int pos = atomicAdd(&cursor[d], 1);
        rec[pos] = make_int2(src[i], __float_as_int(w[i]));
    }
}

// ---------------------------------------------------------------------------
// K1 (MFMA, LDS-free): [P|Q] = [s|x|t] @ Wc1.  K=320.
// Each wave owns 16 rows x 256 cols.  A-frags loaded directly from global
// (lane l: row=base+(l&15), k=kk*32+(l>>4)*8, 32B fp32) -> af[10] in regs.
// B-frags stream from L2 (WC1T [col][k], 16B/lane).  Two col-halves (P,Q)
// keep VGPRs bounded.  No LDS, no barriers.
// ---------------------------------------------------------------------------
__global__ __launch_bounds__(256) void k1_mfma(
    const float* __restrict__ s, const float* __restrict__ x, const float* __restrict__ t,
    const ushort* __restrict__ WC1T, const float* __restrict__ bm1,
    ushort* __restrict__ Pb, ushort* __restrict__ Qb, int N)
{
    int tid = threadIdx.x;
    int w = tid >> 6, l = tid & 63;
    int lr = l & 15;
    int lk = (l >> 4) * 8;
    int nb = blockIdx.x * 64 + w * 16;        // wave row base
    int arow = nb + lr; if (arow > N - 1) arow = N - 1;
    int rbase = (l >> 4) * 4;

    // A fragments for all 10 k-steps
    bf16x8 af[10];
    #pragma unroll
    for (int kk = 0; kk < 10; ++kk) {
        int k = kk * 32 + lk;
        const float* asrc;
        if (k < 128)      asrc = s + (size_t)arow * 128 + k;
        else if (k < 256) asrc = x + (size_t)arow * 128 + (k - 128);
        else              asrc = t + (size_t)arow * 64 + (k - 256);
        float4 f0 = *(const float4*)asrc;
        float4 f1 = *(const float4*)(asrc + 4);
        BF8 pk;
        pk.u[0] = f2bf(f0.x); pk.u[1] = f2bf(f0.y); pk.u[2] = f2bf(f0.z); pk.u[3] = f2bf(f0.w);
        pk.u[4] = f2bf(f1.x); pk.u[5] = f2bf(f1.y); pk.u[6] = f2bf(f1.z); pk.u[7] = f2bf(f1.w);
        af[kk] = pk.v;
    }

    // ---- half 0: cols 0..127 -> P
    {
        f32x4 acc[8];
        #pragma unroll
        for (int i = 0; i < 8; ++i) acc[i] = (f32x4){0.f, 0.f, 0.f, 0.f};
        #pragma unroll
        for (int kk = 0; kk < 10; ++kk) {
            bf16x8 bf[8];
            #pragma unroll
            for (int ct = 0; ct < 8; ++ct)
                bf[ct] = *(const bf16x8*)(WC1T + (size_t)(ct * 16 + lr) * 320 + kk * 32 + lk);
            #pragma unroll
            for (int ct = 0; ct < 8; ++ct)
                acc[ct] = __builtin_amdgcn_mfma_f32_16x16x32_bf16(af[kk], bf[ct], acc[ct], 0, 0, 0);
        }
        #pragma unroll
        for (int ct = 0; ct < 8; ++ct) {
            int col = ct * 16 + lr;
            #pragma unroll
            for (int r = 0; r < 4; ++r) {
                int row = nb + rbase + r;
                if (row < N) Pb[(size_t)row * 128 + col] = f2bf(acc[ct][r]);
            }
        }
    }

    // ---- half 1: cols 128..255 -> Q (+ bm1)
    {
        f32x4 acc[8];
        #pragma unroll
        for (int i = 0; i < 8; ++i) acc[i] = (f32x4){0.f, 0.f, 0.f, 0.f};
        #pragma unroll
        for (int kk = 0; kk < 10; ++kk) {
            bf16x8 bf[8];
            #pragma unroll
            for (int ct = 0; ct < 8; ++ct)
                bf[ct] = *(const bf16x8*)(WC1T + (size_t)(128 + ct * 16 + lr) * 320 + kk * 32 + lk);
            #pragma unroll
            for (int ct = 0; ct < 8; ++ct)
                acc[ct] = __builtin_amdgcn_mfma_f32_16x16x32_bf16(af[kk], bf[ct], acc[ct], 0, 0, 0);
        }
        #pragma unroll
        for (int ct = 0; ct < 8; ++ct) {
            int col = ct * 16 + lr;
            float bb = bm1[col];
            #pragma unroll
            for (int r = 0; r < 4; ++r) {
                int row = nb + rbase + r;
                if (row < N) Qb[(size_t)row * 128 + col] = f2bf(acc[ct][r] + bb);
            }
        }
    }
}

// ---------------------------------------------------------------------------
// K_agg: segmented reduction over dst-sorted edges. One wave per dst node,
// 2 channels/lane.  Scalarized edge loop (readfirstlane bounds, uniform record
// loads), 4-way unroll, branch-free gelu.  No atomics, no shuffles.
// ---------------------------------------------------------------------------
__global__ __launch_bounds__(256) void k_agg(
    const ushort* __restrict__ Pb, const ushort* __restrict__ Qb,
    const int2* __restrict__ rec, const int* __restrict__ offs,
    ushort* __restrict__ GAB, float* __restrict__ sw, int N)
{
    int n = blockIdx.x * 4 + (threadIdx.x >> 6);
    if (n >= N) return;
    int lane = threadIdx.x & 63;
    int beg = __builtin_amdgcn_readfirstlane(offs[n]);
    int end = __builtin_amdgcn_readfirstlane(offs[n + 1]);
    unsigned int qv = *(const unsigned int*)&Qb[(size_t)n * 128 + lane * 2];
    float qx = bfh(qv), qy = bfl(qv);
    float a0 = 0.f, a1 = 0.f, wsum = 0.f;
    int j = beg;
    for (; j + 4 <= end; j += 4) {
        int2 r0 = rec[j];
        int2 r1 = rec[j + 1];
        int2 r2 = rec[j + 2];
        int2 r3 = rec[j + 3];
        unsigned int p0 = *(const unsigned int*)&Pb[(size_t)r0.x * 128 + lane * 2];
        unsigned int p1 = *(const unsigned int*)&Pb[(size_t)r1.x * 128 + lane * 2];
        unsigned int p2 = *(const unsigned int*)&Pb[(size_t)r2.x * 128 + lane * 2];
        unsigned int p3 = *(const unsigned int*)&Pb[(size_t)r3.x * 128 + lane * 2];
        float w0 = __int_as_float(r0.y), w1 = __int_as_float(r1.y);
        float w2 = __int_as_float(r2.y), w3 = __int_as_float(r3.y);
        a0 = fmaf(w0, gelu_fast(bfh(p0) + qx), a0);
        a1 = fmaf(w0, gelu_fast(bfl(p0) + qy), a1);
        a0 = fmaf(w1, gelu_fast(bfh(p1) + qx), a0);
        a1 = fmaf(w1, gelu_fast(bfl(p1) + qy), a1);
        a0 = fmaf(w2, gelu_fast(bfh(p2) + qx), a0);
        a1 = fmaf(w2, gelu_fast(bfl(p2) + qy), a1);
        a0 = fmaf(w3, gelu_fast(bfh(p3) + qx), a0);
        a1 = fmaf(w3, gelu_fast(bfl(p3) + qy), a1);
        wsum += (w0 + w1) + (w2 + w3);
    }
    for (; j < end; ++j) {
        int2 r0 = rec[j];
        unsigned int p0 = *(const unsigned int*)&Pb[(size_t)r0.x * 128 + lane * 2];
        float w0 = __int_as_float(r0.y);
        a0 = fmaf(w0, gelu_fast(bfh(p0) + qx), a0);
        a1 = fmaf(w0, gelu_fast(bfl(p0) + qy), a1);
        wsum += w0;
    }
    *(ushort2*)&GAB[(size_t)n * 128 + lane * 2] = make_ushort2(f2bf(a0), f2bf(a1));
    if (lane == 0) sw[n] = wsum;
}

// ---------------------------------------------------------------------------
// K3 (MFMA): fused update MLP, LDS-free GEMMs + wave-private LDS transpose.
// Wave owns 16 rows x 128 cols.  Phase A: pre2=[s|agg]@Wuc (K=256); epilogue
// gelu -> wave-private H2 (no __syncthreads needed).  Phase B: out=h2@Wu2.
// ---------------------------------------------------------------------------
__global__ __launch_bounds__(256) void k3_mfma(
    const float* __restrict__ s, const ushort* __restrict__ GAB, const float* __restrict__ sw,
    const ushort* __restrict__ WUCT, const float* __restrict__ BV, const float* __restrict__ bu1,
    const ushort* __restrict__ WU2T, const float* __restrict__ bu2,
    float* __restrict__ out, int N)
{
    __shared__ __align__(16) short H2[4][16 * 136];
    int tid = threadIdx.x;
    int w = tid >> 6, l = tid & 63;
    int lr = l & 15, lk = (l >> 4) * 8;
    int nb = blockIdx.x * 64 + w * 16;
    int arow = nb + lr; if (arow > N - 1) arow = N - 1;
    int rbase = (l >> 4) * 4;

    // A fragments (K=256: s then agg)
    bf16x8 af[8];
    #pragma unroll
    for (int kk = 0; kk < 8; ++kk) {
        int k = kk * 32 + lk;
        BF8 pk;
        if (k < 128) {
            const float* asrc = s + (size_t)arow * 128 + k;
            float4 f0 = *(const float4*)asrc;
            float4 f1 = *(const float4*)(asrc + 4);
            pk.u[0] = f2bf(f0.x); pk.u[1] = f2bf(f0.y); pk.u[2] = f2bf(f0.z); pk.u[3] = f2bf(f0.w);
            pk.u[4] = f2bf(f1.x); pk.u[5] = f2bf(f1.y); pk.u[6] = f2bf(f1.z); pk.u[7] = f2bf(f1.w);
            af[kk] = pk.v;
        } else {
            af[kk] = *(const bf16x8*)(GAB + (size_t)arow * 128 + (k - 128));
        }
    }

    // Phase A
    f32x4 acc[8];
    #pragma unroll
    for (int i = 0; i < 8; ++i) acc[i] = (f32x4){0.f, 0.f, 0.f, 0.f};
    #pragma unroll
    for (int kk = 0; kk < 8; ++kk) {
        bf16x8 bf[8];
        #pragma unroll
        for (int ct = 0; ct < 8; ++ct)
            bf[ct] = *(const bf16x8*)(WUCT + (size_t)(ct * 16 + lr) * 256 + kk * 32 + lk);
        #pragma unroll
        for (int ct = 0; ct < 8; ++ct)
            acc[ct] = __builtin_amdgcn_mfma_f32_16x16x32_bf16(af[kk], bf[ct], acc[ct], 0, 0, 0);
    }

    // epilogue A: bias + sw*BV + gelu -> wave-private H2 (bf16)
    float swv[4];
    #pragma unroll
    for (int r = 0; r < 4; ++r) {
        int row = nb + rbase + r;
        swv[r] = (row < N) ? sw[row] : 0.f;
    }
    #pragma unroll
    for (int ct = 0; ct < 8; ++ct) {
        int col = ct * 16 + lr;
        float b1 = bu1[col], bv = BV[col];
        #pragma unroll
        for (int r = 0; r < 4; ++r) {
            float v = acc[ct][r] + b1 + swv[r] * bv;
            H2[w][(rbase + r) * 136 + col] = (short)f2bf(gelu_fast(v));
        }
    }
    // same-wave LDS write->read: compiler inserts lgkmcnt wait; no barrier needed

    // Phase B: out = h2 @ Wu2 (K=128)
    bf16x8 af2[4];
    #pragma unroll
    for (int kk = 0; kk < 4; ++kk)
        af2[kk] = *(const bf16x8*)&H2[w][lr * 136 + kk * 32 + lk];

    f32x4 acc2[8];
    #pragma unroll
    for (int i = 0; i < 8; ++i) acc2[i] = (f32x4){0.f, 0.f, 0.f, 0.f};
    #pragma unroll
    for (int kk = 0; kk < 4; ++kk) {
        bf16x8 bf[8];
        #pragma unroll
        for (int ct = 0; ct < 8; ++ct)
            bf[ct] = *(const bf16x8*)(WU2T + (size_t)(ct * 16 + lr) * 128 + kk * 32 + lk);
        #pragma unroll
        for (int ct = 0; ct < 8; ++ct)
            acc2[ct] = __builtin_amdgcn_mfma_f32_16x16x32_bf16(af2[kk], bf[ct], acc2[ct], 0, 0, 0);
    }

    #pragma unroll
    for (int ct = 0; ct < 8; ++ct) {
        int col = ct * 16 + lr;
        float b2 = bu2[col];
        #pragma unroll
        for (int r = 0; r < 4; ++r) {
            int row = nb + rbase + r;
            if (row < N) out[(size_t)row * 128 + col] = acc2[ct][r] + b2;
        }
    }
}

// ---------------------------------------------------------------------------
extern "C" void kernel_launch(void* const* d_in, const int* in_sizes, int n_in,
                              void* d_out, int out_size, void* d_ws, size_t ws_size,
                              hipStream_t stream) {
    const float* s    = (const float*)d_in[0];
    const float* x    = (const float*)d_in[1];
    const int*   ei   = (const int*)d_in[2];
    const float* ew   = (const float*)d_in[3];
    const float* t    = (const float*)d_in[4];
    const float* Wm1  = (const float*)d_in[5];
    const float* bm1  = (const float*)d_in[6];
    const float* Wm2  = (const float*)d_in[7];
    const float* bm2  = (const float*)d_in[8];
    const float* Wu1  = (const float*)d_in[9];
    const float* bu1  = (const float*)d_in[10];
    const float* Wu2  = (const float*)d_in[11];
    const float* bu2  = (const float*)d_in[12];

    int N = in_sizes[0] / 128;
    int E = in_sizes[2] / 2;
    const int* srcI = ei;
    const int* dstI = ei + E;
    int NP = (N + CHUNK - 1) & ~(CHUNK - 1);
    int C  = NP / CHUNK;

    // workspace layout (32-bit words)
    float* ws = (float*)d_ws;
    size_t off = 0;
    ushort* Pb   = (ushort*)(ws + off); off += (size_t)N * 64;
    ushort* Qb   = (ushort*)(ws + off); off += (size_t)N * 64;
    float*  SW   = ws + off; off += ((size_t)N + 63) & ~(size_t)63;
    ushort* GAB  = (ushort*)(ws + off); off += (size_t)N * 64;
    ushort* WC1T = (ushort*)(ws + off); off += (256 * 320) / 2;
    ushort* WUCT = (ushort*)(ws + off); off += (128 * 256) / 2;
    ushort* WU2T = (ushort*)(ws + off); off += (128 * 128) / 2;
    float*  BV   = ws + off; off += 128;
    int*    DEG  = (int*)(ws + off); off += (size_t)NP;
    int*    OFFS = (int*)(ws + off); off += (size_t)NP + 64;
    int*    CUR  = (int*)(ws + off); off += (size_t)NP;
    int*    CSUM = (int*)(ws + off); off += 128;
    int*    CBASE= (int*)(ws + off); off += 128;
    off = (off + 1) & ~(size_t)1;
    int2*   REC  = (int2*)(ws + off); off += (size_t)E * 2;

    // weight prep
    k_build_wc1t<<<(256 * 320) / 256, 256, 0, stream>>>(Wm1, WC1T);
    k_build_wuct<<<(128 * 256) / 256, 256, 0, stream>>>(Wu1, Wm2, bm2, WUCT, BV);
    k_build_wu2t<<<(128 * 128) / 256, 256, 0, stream>>>(Wu2, WU2T);

    // counting sort by dst (parallel scan)
    k_zero_i<<<(NP + 255) / 256, 256, 0, stream>>>(DEG, NP);
    k_hist<<<(E + 255) / 256, 256, 0, stream>>>(dstI, DEG, E);
    k_chunksum<<<C, 256, 0, stream>>>(DEG, CSUM);
    k_chunkscan<<<1, 64, 0, stream>>>(CSUM, CBASE, C, OFFS, N, E);
    k_chunkoffs<<<C, 256, 0, stream>>>(DEG, CBASE, OFFS, CUR);
    k_scatter<<<(E + 255) / 256, 256, 0, stream>>>(srcI, dstI, ew, CUR, REC, E);

    // node precompute (MFMA, LDS-free)
    int nb = (N + 63) / 64;
    k1_mfma<<<nb, 256, 0, stream>>>(s, x, t, WC1T, bm1, Pb, Qb, N);

    // segmented aggregation
    k_agg<<<(N + 3) / 4, 256, 0, stream>>>(Pb, Qb, REC, OFFS, GAB, SW, N);

    // update MLP (MFMA, fused)
    k3_mfma<<<nb, 256, 0, stream>>>(s, GAB, SW, WUCT, BV, bu1, WU2T, bu2, (float*)d_out, N);
}

// Round 7
// 225.999 us; speedup vs baseline: 1.3841x; 1.3841x over previous
//
#include <hip/hip_runtime.h>
#include <math.h>

#define NHID 128
#define CHUNK 1024

typedef __attribute__((ext_vector_type(8))) short bf16x8;
typedef __attribute__((ext_vector_type(4))) float f32x4;

union BF8 { ushort u[8]; bf16x8 v; };

__device__ __forceinline__ ushort f2bf(float f) {
    unsigned int u = __float_as_uint(f);
    u += 0x7FFFu + ((u >> 16) & 1u);      // round-to-nearest-even
    return (ushort)(u >> 16);
}
__device__ __forceinline__ float bfh(unsigned int v) { return __uint_as_float(v << 16); }
__device__ __forceinline__ float bfl(unsigned int v) { return __uint_as_float(v & 0xffff0000u); }

// Branch-free GELU (A&S 7.1.26 erf, max err ~1.5e-7)
__device__ __forceinline__ float gelu_fast(float x) {
    float ax = fabsf(x);
    float t  = __builtin_amdgcn_rcpf(fmaf(0.23165493f, ax, 1.0f));
    float p  = t * fmaf(t, fmaf(t, fmaf(t, fmaf(t, 1.061405429f, -1.453152027f),
                                        1.421413741f), -0.284496736f), 0.254829592f);
    float e  = __builtin_amdgcn_exp2f(-0.7213475204f * ax * ax);
    float hax = 0.5f * ax;
    return fmaf(-hax, p * e, 0.5f * x + hax);
}

// ---------------------------------------------------------------------------
// Fused weight prep. Fragment-major layouts: element (c,k) of a [C cols][K k]
// matrix goes to ((c/16)*KK + k/32)*512 + (c%16)*32 + (k%32), so a wave's
// MFMA B-fragment (16 cols x 32 k) is ONE contiguous 1024B coalesced load.
//   WC1F: combined msg layer-1, 256 cols x 320 k (KK=10)
//   WUCF: combined update layer-1 (Wm2 folded), 128 cols x 256 k (KK=8)
//   WU2F: update layer-2, 128 cols x 128 k (KK=4);  BV = bm2 @ Wu1_bot
// ---------------------------------------------------------------------------
__global__ __launch_bounds__(256) void k_prep(
    const float* __restrict__ Wm1, const float* __restrict__ Wu1,
    const float* __restrict__ Wm2, const float* __restrict__ bm2,
    ushort* __restrict__ WC1F, ushort* __restrict__ WUCF,
    ushort* __restrict__ WU2F, float* __restrict__ BV)
{
    int bid = blockIdx.x, tid = threadIdx.x;
    if (bid < 320) {                      // WC1F: 81920 elems
        int idx = bid * 256 + tid;
        int c = idx / 320, k = idx % 320;
        float v;
        if (k < 128) {
            v = (c < 128) ? Wm1[k * 128 + c] : Wm1[(128 + k) * 128 + (c - 128)];
        } else if (k < 256) {
            int kk = k - 128;
            v = (c < 128) ? Wm1[(256 + kk) * 128 + c] : -Wm1[(256 + kk) * 128 + (c - 128)];
        } else {
            int kk = k - 256;
            v = (c < 128) ? 0.0f : Wm1[(384 + kk) * 128 + (c - 128)];
        }
        int dst = ((c >> 4) * 10 + (k >> 5)) * 512 + ((c & 15) << 5) + (k & 31);
        WC1F[dst] = f2bf(v);
    } else if (bid < 448) {               // WUCF: 32768 elems
        int idx = (bid - 320) * 256 + tid;
        int c = idx >> 8, k = idx & 255;
        float v;
        if (k < 128) {
            v = Wu1[k * 128 + c];
        } else {
            int i = k - 128;
            float acc = 0.f;
            for (int j = 0; j < 128; ++j) acc += Wm2[i * 128 + j] * Wu1[(128 + j) * 128 + c];
            v = acc;
        }
        int dst = ((c >> 4) * 8 + (k >> 5)) * 512 + ((c & 15) << 5) + (k & 31);
        WUCF[dst] = f2bf(v);
        if (idx < 128) {
            float acc = 0.f;
            for (int j = 0; j < 128; ++j) acc += bm2[j] * Wu1[(128 + j) * 128 + idx];
            BV[idx] = acc;
        }
    }
    // WU2F handled by dedicated kernel arg below (needs Wu2 pointer)
}

__global__ __launch_bounds__(256) void k_prep2(const float* __restrict__ Wu2,
                                               ushort* __restrict__ WU2F) {
    int idx = blockIdx.x * 256 + threadIdx.x;   // 16384
    int c = idx >> 7, k = idx & 127;
    int dst = ((c >> 4) * 4 + (k >> 5)) * 512 + ((c & 15) << 5) + (k & 31);
    WU2F[dst] = f2bf(Wu2[k * 128 + c]);
}

// ---------------------------------------------------------------------------
// Counting sort: zero -> hist -> (chunksum, chunkscan, chunkoffs) -> scatter
// ---------------------------------------------------------------------------
__global__ void k_zero_i(int* __restrict__ p, int n) {
    int i = blockIdx.x * blockDim.x + threadIdx.x;
    if (i < n) p[i] = 0;
}
__global__ void k_hist(const int* __restrict__ dst, int* __restrict__ deg, int E) {
    int i = blockIdx.x * blockDim.x + threadIdx.x;
    if (i < E) atomicAdd(&deg[dst[i]], 1);
}
__global__ __launch_bounds__(256) void k_chunksum(const int* __restrict__ deg,
                                                  int* __restrict__ csum) {
    int c = blockIdx.x, tid = threadIdx.x;
    int4 v = ((const int4*)(deg + (size_t)c * CHUNK))[tid];
    int ts = v.x + v.y + v.z + v.w;
    #pragma unroll
    for (int d = 1; d < 64; d <<= 1) ts += __shfl_xor(ts, d);
    __shared__ int wsum[4];
    if ((tid & 63) == 0) wsum[tid >> 6] = ts;
    __syncthreads();
    if (tid == 0) csum[c] = wsum[0] + wsum[1] + wsum[2] + wsum[3];
}
__global__ void k_chunkscan(const int* __restrict__ csum, int* __restrict__ cbase,
                            int C, int* __restrict__ offs, int N, int E) {
    int lane = threadIdx.x;   // 64
    int carry = 0;
    for (int b = 0; b < C; b += 64) {
        int v = (b + lane < C) ? csum[b + lane] : 0;
        int incl = v;
        #pragma unroll
        for (int d = 1; d < 64; d <<= 1) {
            int t = __shfl_up(incl, d);
            if (lane >= d) incl += t;
        }
        if (b + lane < C) cbase[b + lane] = carry + incl - v;
        carry += __shfl(incl, 63);
    }
    if (lane == 0) offs[N] = E;
}
__global__ __launch_bounds__(256) void k_chunkoffs(const int* __restrict__ deg,
                                                   const int* __restrict__ cbase,
                                                   int* __restrict__ offs,
                                                   int* __restrict__ cursor) {
    int c = blockIdx.x, tid = threadIdx.x;
    int lane = tid & 63, wid = tid >> 6;
    int4 v = ((const int4*)(deg + (size_t)c * CHUNK))[tid];
    int t0 = v.x, t1 = t0 + v.y, t2 = t1 + v.z, ts = t2 + v.w;
    int incl = ts;
    #pragma unroll
    for (int d = 1; d < 64; d <<= 1) {
        int t = __shfl_up(incl, d);
        if (lane >= d) incl += t;
    }
    __shared__ int wz[4];
    if (lane == 63) wz[wid] = incl;
    __syncthreads();
    int wbase = 0;
    for (int k2 = 0; k2 < wid; ++k2) wbase += wz[k2];
    int eb = cbase[c] + wbase + incl - ts;
    int4 o = make_int4(eb, eb + t0, eb + t1, eb + t2);
    ((int4*)(offs + (size_t)c * CHUNK))[tid] = o;
    ((int4*)(cursor + (size_t)c * CHUNK))[tid] = o;
}
__global__ void k_scatter(const int* __restrict__ src, const int* __restrict__ dst,
                          const float* __restrict__ w, int* __restrict__ cursor,
                          int2* __restrict__ rec, int E) {
    int i = blockIdx.x * blockDim.x + threadIdx.x;
    if (i < E) {
        int d = dst[i];
        int pos = atomicAdd(&cursor[d], 1);
        rec[pos] = make_int2(src[i], __float_as_int(w[i]));
    }
}

// ---------------------------------------------------------------------------
// K1 (MFMA): [P|Q] = [s|x|t] @ Wc1.  K=320, 256 out cols, P/Q bf16.
// 32-row blocks (grid ~1563 -> ~6 blocks/CU).  A tile (32x320) staged once to
// LDS, coalesced; one barrier.  Wave w owns cols w*64..+63; B fragments are
// single coalesced 1024B loads from fragment-major WC1F (L2-resident).
// ---------------------------------------------------------------------------
__global__ __launch_bounds__(256) void k1_mfma(
    const float* __restrict__ s, const float* __restrict__ x, const float* __restrict__ t,
    const ushort* __restrict__ WC1F, const float* __restrict__ bm1,
    ushort* __restrict__ Pb, ushort* __restrict__ Qb, int N)
{
    __shared__ __align__(16) short Asub[32 * 328];   // 21KB, stride 164 words = 4 mod 32
    int tid = threadIdx.x;
    int w = tid >> 6, l = tid & 63;
    int lr = l & 15, lkq = l >> 4;
    int lk = lkq * 8;
    int boff = (lr << 5) + (lkq << 3);   // lane offset within a 512-short fragment group
    int n0 = blockIdx.x * 32;

    // ---- stage A tile: row = tid&31, k = 64*c + (tid>>5)*8, c = 0..4
    {
        int ar = tid & 31;
        int kg = (tid >> 5) * 8;
        int arow = n0 + ar; if (arow >= N) arow = N - 1;
        #pragma unroll
        for (int c = 0; c < 5; ++c) {
            int k = c * 64 + kg;
            const float* asrc;
            if (k < 128)      asrc = s + (size_t)arow * 128 + k;
            else if (k < 256) asrc = x + (size_t)arow * 128 + (k - 128);
            else              asrc = t + (size_t)arow * 64 + (k - 256);
            float4 f0 = *(const float4*)asrc;
            float4 f1 = *(const float4*)(asrc + 4);
            BF8 pk;
            pk.u[0] = f2bf(f0.x); pk.u[1] = f2bf(f0.y); pk.u[2] = f2bf(f0.z); pk.u[3] = f2bf(f0.w);
            pk.u[4] = f2bf(f1.x); pk.u[5] = f2bf(f1.y); pk.u[6] = f2bf(f1.z); pk.u[7] = f2bf(f1.w);
            *(bf16x8*)&Asub[ar * 328 + k] = pk.v;
        }
    }
    __syncthreads();

    f32x4 acc[2][4];
    #pragma unroll
    for (int i = 0; i < 2; ++i)
        #pragma unroll
        for (int j = 0; j < 4; ++j) acc[i][j] = (f32x4){0.f, 0.f, 0.f, 0.f};

    const ushort* wbase = WC1F + boff;
    #pragma unroll
    for (int kk = 0; kk < 10; ++kk) {
        bf16x8 b[4];
        #pragma unroll
        for (int ct = 0; ct < 4; ++ct) {
            int g = w * 4 + ct;
            b[ct] = *(const bf16x8*)(wbase + (size_t)(g * 10 + kk) * 512);
        }
        bf16x8 a0 = *(const bf16x8*)&Asub[lr * 328 + kk * 32 + lk];
        bf16x8 a1 = *(const bf16x8*)&Asub[(16 + lr) * 328 + kk * 32 + lk];
        #pragma unroll
        for (int ct = 0; ct < 4; ++ct) {
            acc[0][ct] = __builtin_amdgcn_mfma_f32_16x16x32_bf16(a0, b[ct], acc[0][ct], 0, 0, 0);
            acc[1][ct] = __builtin_amdgcn_mfma_f32_16x16x32_bf16(a1, b[ct], acc[1][ct], 0, 0, 0);
        }
    }

    int rbase = lkq * 4;
    #pragma unroll
    for (int ct = 0; ct < 4; ++ct) {
        int col = w * 64 + ct * 16 + lr;
        float bb = (col >= 128) ? bm1[col - 128] : 0.f;
        #pragma unroll
        for (int rt = 0; rt < 2; ++rt) {
            #pragma unroll
            for (int r = 0; r < 4; ++r) {
                int row = n0 + rt * 16 + rbase + r;
                if (row < N) {
                    float v = acc[rt][ct][r];
                    if (col < 128) Pb[(size_t)row * 128 + col] = f2bf(v);
                    else           Qb[(size_t)row * 128 + (col - 128)] = f2bf(v + bb);
                }
            }
        }
    }
}

// ---------------------------------------------------------------------------
// K_agg: segmented reduction over dst-sorted edges, one wave per dst node,
// 2 ch/lane.  Software-pipelined: records+P loads one batch ahead of math.
// ---------------------------------------------------------------------------
__global__ __launch_bounds__(256) void k_agg(
    const ushort* __restrict__ Pb, const ushort* __restrict__ Qb,
    const int2* __restrict__ rec, const int* __restrict__ offs,
    ushort* __restrict__ GAB, float* __restrict__ sw, int N)
{
    int n = blockIdx.x * 4 + (threadIdx.x >> 6);
    if (n >= N) return;
    int lane = threadIdx.x & 63;
    int beg = __builtin_amdgcn_readfirstlane(offs[n]);
    int end = __builtin_amdgcn_readfirstlane(offs[n + 1]);
    unsigned int qv = *(const unsigned int*)&Qb[(size_t)n * 128 + lane * 2];
    float qx = bfh(qv), qy = bfl(qv);
    float a0 = 0.f, a1 = 0.f, wsum = 0.f;
    int j = beg;
    if (j + 4 <= end) {
        int2 r0 = rec[j], r1 = rec[j + 1], r2 = rec[j + 2], r3 = rec[j + 3];
        unsigned int p0 = *(const unsigned int*)&Pb[(size_t)r0.x * 128 + lane * 2];
        unsigned int p1 = *(const unsigned int*)&Pb[(size_t)r1.x * 128 + lane * 2];
        unsigned int p2 = *(const unsigned int*)&Pb[(size_t)r2.x * 128 + lane * 2];
        unsigned int p3 = *(const unsigned int*)&Pb[(size_t)r3.x * 128 + lane * 2];
        j += 4;
        while (j + 4 <= end) {
            int2 s0 = rec[j], s1 = rec[j + 1], s2 = rec[j + 2], s3 = rec[j + 3];
            unsigned int n0_ = *(const unsigned int*)&Pb[(size_t)s0.x * 128 + lane * 2];
            unsigned int n1_ = *(const unsigned int*)&Pb[(size_t)s1.x * 128 + lane * 2];
            unsigned int n2_ = *(const unsigned int*)&Pb[(size_t)s2.x * 128 + lane * 2];
            unsigned int n3_ = *(const unsigned int*)&Pb[(size_t)s3.x * 128 + lane * 2];
            float w0 = __int_as_float(r0.y), w1 = __int_as_float(r1.y);
            float w2 = __int_as_float(r2.y), w3 = __int_as_float(r3.y);
            a0 = fmaf(w0, gelu_fast(bfh(p0) + qx), a0);
            a1 = fmaf(w0, gelu_fast(bfl(p0) + qy), a1);
            a0 = fmaf(w1, gelu_fast(bfh(p1) + qx), a0);
            a1 = fmaf(w1, gelu_fast(bfl(p1) + qy), a1);
            a0 = fmaf(w2, gelu_fast(bfh(p2) + qx), a0);
            a1 = fmaf(w2, gelu_fast(bfl(p2) + qy), a1);
            a0 = fmaf(w3, gelu_fast(bfh(p3) + qx), a0);
            a1 = fmaf(w3, gelu_fast(bfl(p3) + qy), a1);
            wsum += (w0 + w1) + (w2 + w3);
            r0 = s0; r1 = s1; r2 = s2; r3 = s3;
            p0 = n0_; p1 = n1_; p2 = n2_; p3 = n3_;
            j += 4;
        }
        // drain last full batch
        float w0 = __int_as_float(r0.y), w1 = __int_as_float(r1.y);
        float w2 = __int_as_float(r2.y), w3 = __int_as_float(r3.y);
        a0 = fmaf(w0, gelu_fast(bfh(p0) + qx), a0);
        a1 = fmaf(w0, gelu_fast(bfl(p0) + qy), a1);
        a0 = fmaf(w1, gelu_fast(bfh(p1) + qx), a0);
        a1 = fmaf(w1, gelu_fast(bfl(p1) + qy), a1);
        a0 = fmaf(w2, gelu_fast(bfh(p2) + qx), a0);
        a1 = fmaf(w2, gelu_fast(bfl(p2) + qy), a1);
        a0 = fmaf(w3, gelu_fast(bfh(p3) + qx), a0);
        a1 = fmaf(w3, gelu_fast(bfl(p3) + qy), a1);
        wsum += (w0 + w1) + (w2 + w3);
    }
    for (; j < end; ++j) {
        int2 r0 = rec[j];
        unsigned int p0 = *(const unsigned int*)&Pb[(size_t)r0.x * 128 + lane * 2];
        float w0 = __int_as_float(r0.y);
        a0 = fmaf(w0, gelu_fast(bfh(p0) + qx), a0);
        a1 = fmaf(w0, gelu_fast(bfl(p0) + qy), a1);
        wsum += w0;
    }
    *(ushort2*)&GAB[(size_t)n * 128 + lane * 2] = make_ushort2(f2bf(a0), f2bf(a1));
    if (lane == 0) sw[n] = wsum;
}

// ---------------------------------------------------------------------------
// K3 (MFMA): fused update MLP, 32-row blocks (grid ~1563).
// Phase A: pre2 = [s|agg] @ Wuc (K=256), A staged once; wave w owns cols
// w*32..+31.  Epilogue gelu -> H2 (LDS).  Barrier.  Phase B: out = h2 @ Wu2.
// B frags: coalesced 1024B loads from fragment-major WUCF / WU2F.
// ---------------------------------------------------------------------------
__global__ __launch_bounds__(256) void k3_mfma(
    const float* __restrict__ s, const ushort* __restrict__ GAB, const float* __restrict__ sw,
    const ushort* __restrict__ WUCF, const float* __restrict__ BV, const float* __restrict__ bu1,
    const ushort* __restrict__ WU2F, const float* __restrict__ bu2,
    float* __restrict__ out, int N)
{
    __shared__ __align__(16) short Asub[32 * 264];   // 16.5KB
    __shared__ __align__(16) short H2[32 * 136];     // 8.7KB
    __shared__ float SWs[32];
    int tid = threadIdx.x;
    int w = tid >> 6, l = tid & 63;
    int lr = l & 15, lkq = l >> 4;
    int lk = lkq * 8;
    int boff = (lr << 5) + (lkq << 3);
    int n0 = blockIdx.x * 32;

    if (tid < 32) SWs[tid] = (n0 + tid < N) ? sw[n0 + tid] : 0.f;

    // ---- stage A tile ([s|agg], K=256): row = tid&31, k = 64*c + (tid>>5)*8
    {
        int ar = tid & 31;
        int kg = (tid >> 5) * 8;
        int arow = n0 + ar; if (arow >= N) arow = N - 1;
        #pragma unroll
        for (int c = 0; c < 4; ++c) {
            int k = c * 64 + kg;
            BF8 pk;
            if (k < 128) {
                const float* asrc = s + (size_t)arow * 128 + k;
                float4 f0 = *(const float4*)asrc;
                float4 f1 = *(const float4*)(asrc + 4);
                pk.u[0] = f2bf(f0.x); pk.u[1] = f2bf(f0.y); pk.u[2] = f2bf(f0.z); pk.u[3] = f2bf(f0.w);
                pk.u[4] = f2bf(f1.x); pk.u[5] = f2bf(f1.y); pk.u[6] = f2bf(f1.z); pk.u[7] = f2bf(f1.w);
            } else {
                pk.v = *(const bf16x8*)(GAB + (size_t)arow * 128 + (k - 128));
            }
            *(bf16x8*)&Asub[ar * 264 + k] = pk.v;
        }
    }
    __syncthreads();

    // ---- Phase A: wave w -> cols w*32..+31 (groups g = w*2, w*2+1)
    f32x4 acc[2][2];
    #pragma unroll
    for (int i = 0; i < 2; ++i) { acc[i][0] = (f32x4){0,0,0,0}; acc[i][1] = (f32x4){0,0,0,0}; }

    #pragma unroll
    for (int kk = 0; kk < 8; ++kk) {
        bf16x8 b[2];
        #pragma unroll
        for (int ct = 0; ct < 2; ++ct) {
            int g = w * 2 + ct;
            b[ct] = *(const bf16x8*)(WUCF + (size_t)(g * 8 + kk) * 512 + boff);
        }
        bf16x8 a0 = *(const bf16x8*)&Asub[lr * 264 + kk * 32 + lk];
        bf16x8 a1 = *(const bf16x8*)&Asub[(16 + lr) * 264 + kk * 32 + lk];
        #pragma unroll
        for (int ct = 0; ct < 2; ++ct) {
            acc[0][ct] = __builtin_amdgcn_mfma_f32_16x16x32_bf16(a0, b[ct], acc[0][ct], 0, 0, 0);
            acc[1][ct] = __builtin_amdgcn_mfma_f32_16x16x32_bf16(a1, b[ct], acc[1][ct], 0, 0, 0);
        }
    }

    int rbase = lkq * 4;
    #pragma unroll
    for (int ct = 0; ct < 2; ++ct) {
        int col = w * 32 + ct * 16 + lr;
        float b1 = bu1[col], bv = BV[col];
        #pragma unroll
        for (int rt = 0; rt < 2; ++rt) {
            #pragma unroll
            for (int r = 0; r < 4; ++r) {
                int row16 = rt * 16 + rbase + r;
                float v = acc[rt][ct][r] + b1 + SWs[row16] * bv;
                H2[row16 * 136 + col] = (short)f2bf(gelu_fast(v));
            }
        }
    }
    __syncthreads();

    // ---- Phase B: out = h2 @ Wu2 (K=128)
    f32x4 acc2[2][2];
    #pragma unroll
    for (int i = 0; i < 2; ++i) { acc2[i][0] = (f32x4){0,0,0,0}; acc2[i][1] = (f32x4){0,0,0,0}; }

    #pragma unroll
    for (int kk = 0; kk < 4; ++kk) {
        bf16x8 b[2];
        #pragma unroll
        for (int ct = 0; ct < 2; ++ct) {
            int g = w * 2 + ct;
            b[ct] = *(const bf16x8*)(WU2F + (size_t)(g * 4 + kk) * 512 + boff);
        }
        bf16x8 a0 = *(const bf16x8*)&H2[lr * 136 + kk * 32 + lk];
        bf16x8 a1 = *(const bf16x8*)&H2[(16 + lr) * 136 + kk * 32 + lk];
        #pragma unroll
        for (int ct = 0; ct < 2; ++ct) {
            acc2[0][ct] = __builtin_amdgcn_mfma_f32_16x16x32_bf16(a0, b[ct], acc2[0][ct], 0, 0, 0);
            acc2[1][ct] = __builtin_amdgcn_mfma_f32_16x16x32_bf16(a1, b[ct], acc2[1][ct], 0, 0, 0);
        }
    }

    #pragma unroll
    for (int ct = 0; ct < 2; ++ct) {
        int col = w * 32 + ct * 16 + lr;
        float b2 = bu2[col];
        #pragma unroll
        for (int rt = 0; rt < 2; ++rt) {
            #pragma unroll
            for (int r = 0; r < 4; ++r) {
                int row = n0 + rt * 16 + rbase + r;
                if (row < N) out[(size_t)row * 128 + col] = acc2[rt][ct][r] + b2;
            }
        }
    }
}

// ---------------------------------------------------------------------------
extern "C" void kernel_launch(void* const* d_in, const int* in_sizes, int n_in,
                              void* d_out, int out_size, void* d_ws, size_t ws_size,
                              hipStream_t stream) {
    const float* s    = (const float*)d_in[0];
    const float* x    = (const float*)d_in[1];
    const int*   ei   = (const int*)d_in[2];
    const float* ew   = (const float*)d_in[3];
    const float* t    = (const float*)d_in[4];
    const float* Wm1  = (const float*)d_in[5];
    const float* bm1  = (const float*)d_in[6];
    const float* Wm2  = (const float*)d_in[7];
    const float* bm2  = (const float*)d_in[8];
    const float* Wu1  = (const float*)d_in[9];
    const float* bu1  = (const float*)d_in[10];
    const float* Wu2  = (const float*)d_in[11];
    const float* bu2  = (const float*)d_in[12];

    int N = in_sizes[0] / 128;
    int E = in_sizes[2] / 2;
    const int* srcI = ei;
    const int* dstI = ei + E;
    int NP = (N + CHUNK - 1) & ~(CHUNK - 1);
    int C  = NP / CHUNK;

    // workspace layout (32-bit words), 16B-aligned chunks
    float* ws = (float*)d_ws;
    size_t off = 0;
    ushort* Pb   = (ushort*)(ws + off); off += (size_t)N * 64;
    ushort* Qb   = (ushort*)(ws + off); off += (size_t)N * 64;
    float*  SW   = ws + off; off += ((size_t)N + 63) & ~(size_t)63;
    ushort* GAB  = (ushort*)(ws + off); off += (size_t)N * 64;
    ushort* WC1F = (ushort*)(ws + off); off += (256 * 320) / 2;
    ushort* WUCF = (ushort*)(ws + off); off += (128 * 256) / 2;
    ushort* WU2F = (ushort*)(ws + off); off += (128 * 128) / 2;
    float*  BV   = ws + off; off += 128;
    int*    DEG  = (int*)(ws + off); off += (size_t)NP;
    int*    OFFS = (int*)(ws + off); off += (size_t)NP + 64;
    off = (off + 3) & ~(size_t)3;
    int*    CUR  = (int*)(ws + off); off += (size_t)NP;
    int*    CSUM = (int*)(ws + off); off += 128;
    int*    CBASE= (int*)(ws + off); off += 128;
    off = (off + 3) & ~(size_t)3;
    int2*   REC  = (int2*)(ws + off); off += (size_t)E * 2;

    // weight prep (fused)
    k_prep<<<448, 256, 0, stream>>>(Wm1, Wu1, Wm2, bm2, WC1F, WUCF, WU2F, BV);
    k_prep2<<<64, 256, 0, stream>>>(Wu2, WU2F);

    // counting sort by dst (parallel scan)
    k_zero_i<<<(NP + 255) / 256, 256, 0, stream>>>(DEG, NP);
    k_hist<<<(E + 255) / 256, 256, 0, stream>>>(dstI, DEG, E);
    k_chunksum<<<C, 256, 0, stream>>>(DEG, CSUM);
    k_chunkscan<<<1, 64, 0, stream>>>(CSUM, CBASE, C, OFFS, N, E);
    k_chunkoffs<<<C, 256, 0, stream>>>(DEG, CBASE, OFFS, CUR);
    k_scatter<<<(E + 255) / 256, 256, 0, stream>>>(srcI, dstI, ew, CUR, REC, E);

    // node precompute (MFMA, 32-row blocks, coalesced fragment loads)
    int nb32 = (N + 31) / 32;
    k1_mfma<<<nb32, 256, 0, stream>>>(s, x, t, WC1F, bm1, Pb, Qb, N);

    // segmented aggregation (pipelined)
    k_agg<<<(N + 3) / 4, 256, 0, stream>>>(Pb, Qb, REC, OFFS, GAB, SW, N);

    // update MLP (MFMA, fused, 32-row blocks)
    k3_mfma<<<nb32, 256, 0, stream>>>(s, GAB, SW, WUCF, BV, bu1, WU2F, bu2, (float*)d_out, N);
}

// Round 10
// 220.425 us; speedup vs baseline: 1.4191x; 1.0253x over previous
//
#include <hip/hip_runtime.h>
#include <math.h>

#define NHID 128
#define CHUNK 1024

typedef __attribute__((ext_vector_type(8))) short bf16x8;
typedef __attribute__((ext_vector_type(4))) float f32x4;

union BF8 { ushort u[8]; bf16x8 v; };

__device__ __forceinline__ ushort f2bf(float f) {
    unsigned int u = __float_as_uint(f);
    u += 0x7FFFu + ((u >> 16) & 1u);      // round-to-nearest-even
    return (ushort)(u >> 16);
}
__device__ __forceinline__ float bfh(unsigned int v) { return __uint_as_float(v << 16); }
__device__ __forceinline__ float bfl(unsigned int v) { return __uint_as_float(v & 0xffff0000u); }

// Branch-free GELU (A&S 7.1.26 erf, max err ~1.5e-7) — scalar, known-good.
// NOTE: inline-asm v_pk_fma_f32 gelu failed correctness twice (rounds 8-9,
// absmax ~0.4): VOP3P packed-FP32 asm semantics (op_sel_hi defaults) are not
// what the plain mnemonic suggests. Do not reintroduce without an isolated probe.
__device__ __forceinline__ float gelu_fast(float x) {
    float ax = fabsf(x);
    float t  = __builtin_amdgcn_rcpf(fmaf(0.23165493f, ax, 1.0f));
    float p  = t * fmaf(t, fmaf(t, fmaf(t, fmaf(t, 1.061405429f, -1.453152027f),
                                        1.421413741f), -0.284496736f), 0.254829592f);
    float e  = __builtin_amdgcn_exp2f(-0.7213475204f * ax * ax);
    float hax = 0.5f * ax;
    return fmaf(-hax, p * e, 0.5f * x + hax);
}

// ---------------------------------------------------------------------------
// Fused weight prep + edge histogram.  Fragment-major weights: element (c,k)
// of [C][K] -> ((c/16)*KK + k/32)*512 + (c%16)*32 + (k%32): one 1024B
// coalesced B-frag load per wave.
//   blocks 0-319   : WC1F (256 cols x 320 k, KK=10)
//   blocks 320-447 : WUCF (128 cols x 256 k, KK=8) + BV
//   blocks 448-511 : WU2F (128 cols x 128 k, KK=4)
//   blocks 512+    : histogram of dst into DEG (DEG memset'd beforehand)
// ---------------------------------------------------------------------------
__global__ __launch_bounds__(256) void k_prep(
    const float* __restrict__ Wm1, const float* __restrict__ Wu1,
    const float* __restrict__ Wm2, const float* __restrict__ bm2,
    const float* __restrict__ Wu2, const int* __restrict__ dstI, int E,
    ushort* __restrict__ WC1F, ushort* __restrict__ WUCF,
    ushort* __restrict__ WU2F, float* __restrict__ BV, int* __restrict__ deg)
{
    int bid = blockIdx.x, tid = threadIdx.x;
    if (bid < 320) {                      // WC1F
        int idx = bid * 256 + tid;
        int c = idx / 320, k = idx % 320;
        float v;
        if (k < 128) {
            v = (c < 128) ? Wm1[k * 128 + c] : Wm1[(128 + k) * 128 + (c - 128)];
        } else if (k < 256) {
            int kk = k - 128;
            v = (c < 128) ? Wm1[(256 + kk) * 128 + c] : -Wm1[(256 + kk) * 128 + (c - 128)];
        } else {
            int kk = k - 256;
            v = (c < 128) ? 0.0f : Wm1[(384 + kk) * 128 + (c - 128)];
        }
        int dst = ((c >> 4) * 10 + (k >> 5)) * 512 + ((c & 15) << 5) + (k & 31);
        WC1F[dst] = f2bf(v);
    } else if (bid < 448) {               // WUCF + BV
        int idx = (bid - 320) * 256 + tid;
        int c = idx >> 8, k = idx & 255;
        float v;
        if (k < 128) {
            v = Wu1[k * 128 + c];
        } else {
            int i = k - 128;
            float acc = 0.f;
            for (int j = 0; j < 128; ++j) acc += Wm2[i * 128 + j] * Wu1[(128 + j) * 128 + c];
            v = acc;
        }
        int dst = ((c >> 4) * 8 + (k >> 5)) * 512 + ((c & 15) << 5) + (k & 31);
        WUCF[dst] = f2bf(v);
        if (idx < 128) {
            float acc = 0.f;
            for (int j = 0; j < 128; ++j) acc += bm2[j] * Wu1[(128 + j) * 128 + idx];
            BV[idx] = acc;
        }
    } else if (bid < 512) {               // WU2F
        int idx = (bid - 448) * 256 + tid;
        int c = idx >> 7, k = idx & 127;
        int dst = ((c >> 4) * 4 + (k >> 5)) * 512 + ((c & 15) << 5) + (k & 31);
        WU2F[dst] = f2bf(Wu2[k * 128 + c]);
    } else {                              // histogram
        int i = (bid - 512) * 256 + tid;
        if (i < E) atomicAdd(&deg[dstI[i]], 1);
    }
}

// ---------------------------------------------------------------------------
// Counting sort tail: chunksum -> chunkscan -> chunkoffs -> scatter
// ---------------------------------------------------------------------------
__global__ __launch_bounds__(256) void k_chunksum(const int* __restrict__ deg,
                                                  int* __restrict__ csum) {
    int c = blockIdx.x, tid = threadIdx.x;
    int4 v = ((const int4*)(deg + (size_t)c * CHUNK))[tid];
    int ts = v.x + v.y + v.z + v.w;
    #pragma unroll
    for (int d = 1; d < 64; d <<= 1) ts += __shfl_xor(ts, d);
    __shared__ int wsum[4];
    if ((tid & 63) == 0) wsum[tid >> 6] = ts;
    __syncthreads();
    if (tid == 0) csum[c] = wsum[0] + wsum[1] + wsum[2] + wsum[3];
}
__global__ void k_chunkscan(const int* __restrict__ csum, int* __restrict__ cbase,
                            int C, int* __restrict__ offs, int N, int E) {
    int lane = threadIdx.x;   // 64
    int carry = 0;
    for (int b = 0; b < C; b += 64) {
        int v = (b + lane < C) ? csum[b + lane] : 0;
        int incl = v;
        #pragma unroll
        for (int d = 1; d < 64; d <<= 1) {
            int t = __shfl_up(incl, d);
            if (lane >= d) incl += t;
        }
        if (b + lane < C) cbase[b + lane] = carry + incl - v;
        carry += __shfl(incl, 63);
    }
    if (lane == 0) offs[N] = E;
}
__global__ __launch_bounds__(256) void k_chunkoffs(const int* __restrict__ deg,
                                                   const int* __restrict__ cbase,
                                                   int* __restrict__ offs,
                                                   int* __restrict__ cursor) {
    int c = blockIdx.x, tid = threadIdx.x;
    int lane = tid & 63, wid = tid >> 6;
    int4 v = ((const int4*)(deg + (size_t)c * CHUNK))[tid];
    int t0 = v.x, t1 = t0 + v.y, t2 = t1 + v.z, ts = t2 + v.w;
    int incl = ts;
    #pragma unroll
    for (int d = 1; d < 64; d <<= 1) {
        int t = __shfl_up(incl, d);
        if (lane >= d) incl += t;
    }
    __shared__ int wz[4];
    if (lane == 63) wz[wid] = incl;
    __syncthreads();
    int wbase = 0;
    for (int k2 = 0; k2 < wid; ++k2) wbase += wz[k2];
    int eb = cbase[c] + wbase + incl - ts;
    int4 o = make_int4(eb, eb + t0, eb + t1, eb + t2);
    ((int4*)(offs + (size_t)c * CHUNK))[tid] = o;
    ((int4*)(cursor + (size_t)c * CHUNK))[tid] = o;
}
__global__ void k_scatter(const int* __restrict__ src, const int* __restrict__ dst,
                          const float* __restrict__ w, int* __restrict__ cursor,
                          int2* __restrict__ rec, int E) {
    int i = blockIdx.x * blockDim.x + threadIdx.x;
    if (i < E) {
        int d = dst[i];
        int pos = atomicAdd(&cursor[d], 1);
        rec[pos] = make_int2(src[i], __float_as_int(w[i]));
    }
}

// ---------------------------------------------------------------------------
// K1 (MFMA): [P|Q] = [s|x|t] @ Wc1.  32-row blocks, A staged once, B frags
// single coalesced 1024B loads from fragment-major WC1F (L2-resident).
// ---------------------------------------------------------------------------
__global__ __launch_bounds__(256) void k1_mfma(
    const float* __restrict__ s, const float* __restrict__ x, const float* __restrict__ t,
    const ushort* __restrict__ WC1F, const float* __restrict__ bm1,
    ushort* __restrict__ Pb, ushort* __restrict__ Qb, int N)
{
    __shared__ __align__(16) short Asub[32 * 328];
    int tid = threadIdx.x;
    int w = tid >> 6, l = tid & 63;
    int lr = l & 15, lkq = l >> 4;
    int lk = lkq * 8;
    int boff = (lr << 5) + (lkq << 3);
    int n0 = blockIdx.x * 32;

    {
        int ar = tid & 31;
        int kg = (tid >> 5) * 8;
        int arow = n0 + ar; if (arow >= N) arow = N - 1;
        #pragma unroll
        for (int c = 0; c < 5; ++c) {
            int k = c * 64 + kg;
            const float* asrc;
            if (k < 128)      asrc = s + (size_t)arow * 128 + k;
            else if (k < 256) asrc = x + (size_t)arow * 128 + (k - 128);
            else              asrc = t + (size_t)arow * 64 + (k - 256);
            float4 f0 = *(const float4*)asrc;
            float4 f1 = *(const float4*)(asrc + 4);
            BF8 pk;
            pk.u[0] = f2bf(f0.x); pk.u[1] = f2bf(f0.y); pk.u[2] = f2bf(f0.z); pk.u[3] = f2bf(f0.w);
            pk.u[4] = f2bf(f1.x); pk.u[5] = f2bf(f1.y); pk.u[6] = f2bf(f1.z); pk.u[7] = f2bf(f1.w);
            *(bf16x8*)&Asub[ar * 328 + k] = pk.v;
        }
    }
    __syncthreads();

    f32x4 acc[2][4];
    #pragma unroll
    for (int i = 0; i < 2; ++i)
        #pragma unroll
        for (int j = 0; j < 4; ++j) acc[i][j] = (f32x4){0.f, 0.f, 0.f, 0.f};

    const ushort* wbase = WC1F + boff;
    #pragma unroll
    for (int kk = 0; kk < 10; ++kk) {
        bf16x8 b[4];
        #pragma unroll
        for (int ct = 0; ct < 4; ++ct) {
            int g = w * 4 + ct;
            b[ct] = *(const bf16x8*)(wbase + (size_t)(g * 10 + kk) * 512);
        }
        bf16x8 a0 = *(const bf16x8*)&Asub[lr * 328 + kk * 32 + lk];
        bf16x8 a1 = *(const bf16x8*)&Asub[(16 + lr) * 328 + kk * 32 + lk];
        #pragma unroll
        for (int ct = 0; ct < 4; ++ct) {
            acc[0][ct] = __builtin_amdgcn_mfma_f32_16x16x32_bf16(a0, b[ct], acc[0][ct], 0, 0, 0);
            acc[1][ct] = __builtin_amdgcn_mfma_f32_16x16x32_bf16(a1, b[ct], acc[1][ct], 0, 0, 0);
        }
    }

    int rbase = lkq * 4;
    #pragma unroll
    for (int ct = 0; ct < 4; ++ct) {
        int col = w * 64 + ct * 16 + lr;
        float bb = (col >= 128) ? bm1[col - 128] : 0.f;
        #pragma unroll
        for (int rt = 0; rt < 2; ++rt) {
            #pragma unroll
            for (int r = 0; r < 4; ++r) {
                int row = n0 + rt * 16 + rbase + r;
                if (row < N) {
                    float v = acc[rt][ct][r];
                    if (col < 128) Pb[(size_t)row * 128 + col] = f2bf(v);
                    else           Qb[(size_t)row * 128 + (col - 128)] = f2bf(v + bb);
                }
            }
        }
    }
}

// ---------------------------------------------------------------------------
// K_agg: segmented reduction, one wave per dst node, 2 ch/lane.
// Software-pipelined gathers; scalar gelu (known-good); 32-bit offsets.
// ---------------------------------------------------------------------------
__global__ __launch_bounds__(256) void k_agg(
    const ushort* __restrict__ Pb, const ushort* __restrict__ Qb,
    const int2* __restrict__ rec, const int* __restrict__ offs,
    ushort* __restrict__ GAB, float* __restrict__ sw, int N)
{
    int n = blockIdx.x * 4 + (threadIdx.x >> 6);
    if (n >= N) return;
    int lane = threadIdx.x & 63;
    unsigned lo2 = (unsigned)(lane << 1);
    int beg = __builtin_amdgcn_readfirstlane(offs[n]);
    int end = __builtin_amdgcn_readfirstlane(offs[n + 1]);
    unsigned int qv = *(const unsigned int*)&Qb[((unsigned)n << 7) + lo2];
    float qx = bfh(qv), qy = bfl(qv);
    float a0 = 0.f, a1 = 0.f, wsum = 0.f;
    int j = beg;
    if (j + 4 <= end) {
        int2 r0 = rec[j], r1 = rec[j + 1], r2 = rec[j + 2], r3 = rec[j + 3];
        unsigned int p0 = *(const unsigned int*)&Pb[((unsigned)r0.x << 7) + lo2];
        unsigned int p1 = *(const unsigned int*)&Pb[((unsigned)r1.x << 7) + lo2];
        unsigned int p2 = *(const unsigned int*)&Pb[((unsigned)r2.x << 7) + lo2];
        unsigned int p3 = *(const unsigned int*)&Pb[((unsigned)r3.x << 7) + lo2];
        j += 4;
        while (j + 4 <= end) {
            int2 s0 = rec[j], s1 = rec[j + 1], s2 = rec[j + 2], s3 = rec[j + 3];
            unsigned int n0_ = *(const unsigned int*)&Pb[((unsigned)s0.x << 7) + lo2];
            unsigned int n1_ = *(const unsigned int*)&Pb[((unsigned)s1.x << 7) + lo2];
            unsigned int n2_ = *(const unsigned int*)&Pb[((unsigned)s2.x << 7) + lo2];
            unsigned int n3_ = *(const unsigned int*)&Pb[((unsigned)s3.x << 7) + lo2];
            float w0 = __int_as_float(r0.y), w1 = __int_as_float(r1.y);
            float w2 = __int_as_float(r2.y), w3 = __int_as_float(r3.y);
            a0 = fmaf(w0, gelu_fast(bfh(p0) + qx), a0);
            a1 = fmaf(w0, gelu_fast(bfl(p0) + qy), a1);
            a0 = fmaf(w1, gelu_fast(bfh(p1) + qx), a0);
            a1 = fmaf(w1, gelu_fast(bfl(p1) + qy), a1);
            a0 = fmaf(w2, gelu_fast(bfh(p2) + qx), a0);
            a1 = fmaf(w2, gelu_fast(bfl(p2) + qy), a1);
            a0 = fmaf(w3, gelu_fast(bfh(p3) + qx), a0);
            a1 = fmaf(w3, gelu_fast(bfl(p3) + qy), a1);
            wsum += (w0 + w1) + (w2 + w3);
            r0 = s0; r1 = s1; r2 = s2; r3 = s3;
            p0 = n0_; p1 = n1_; p2 = n2_; p3 = n3_;
            j += 4;
        }
        float w0 = __int_as_float(r0.y), w1 = __int_as_float(r1.y);
        float w2 = __int_as_float(r2.y), w3 = __int_as_float(r3.y);
        a0 = fmaf(w0, gelu_fast(bfh(p0) + qx), a0);
        a1 = fmaf(w0, gelu_fast(bfl(p0) + qy), a1);
        a0 = fmaf(w1, gelu_fast(bfh(p1) + qx), a0);
        a1 = fmaf(w1, gelu_fast(bfl(p1) + qy), a1);
        a0 = fmaf(w2, gelu_fast(bfh(p2) + qx), a0);
        a1 = fmaf(w2, gelu_fast(bfl(p2) + qy), a1);
        a0 = fmaf(w3, gelu_fast(bfh(p3) + qx), a0);
        a1 = fmaf(w3, gelu_fast(bfl(p3) + qy), a1);
        wsum += (w0 + w1) + (w2 + w3);
    }
    for (; j < end; ++j) {
        int2 r0 = rec[j];
        unsigned int p0 = *(const unsigned int*)&Pb[((unsigned)r0.x << 7) + lo2];
        float w0 = __int_as_float(r0.y);
        a0 = fmaf(w0, gelu_fast(bfh(p0) + qx), a0);
        a1 = fmaf(w0, gelu_fast(bfl(p0) + qy), a1);
        wsum += w0;
    }
    *(ushort2*)&GAB[((unsigned)n << 7) + lo2] = make_ushort2(f2bf(a0), f2bf(a1));
    if (lane == 0) sw[n] = wsum;
}

// ---------------------------------------------------------------------------
// K3 (MFMA): fused update MLP, 32-row blocks, fragment-major B.
// ---------------------------------------------------------------------------
__global__ __launch_bounds__(256) void k3_mfma(
    const float* __restrict__ s, const ushort* __restrict__ GAB, const float* __restrict__ sw,
    const ushort* __restrict__ WUCF, const float* __restrict__ BV, const float* __restrict__ bu1,
    const ushort* __restrict__ WU2F, const float* __restrict__ bu2,
    float* __restrict__ out, int N)
{
    __shared__ __align__(16) short Asub[32 * 264];
    __shared__ __align__(16) short H2[32 * 136];
    __shared__ float SWs[32];
    int tid = threadIdx.x;
    int w = tid >> 6, l = tid & 63;
    int lr = l & 15, lkq = l >> 4;
    int lk = lkq * 8;
    int boff = (lr << 5) + (lkq << 3);
    int n0 = blockIdx.x * 32;

    if (tid < 32) SWs[tid] = (n0 + tid < N) ? sw[n0 + tid] : 0.f;

    {
        int ar = tid & 31;
        int kg = (tid >> 5) * 8;
        int arow = n0 + ar; if (arow >= N) arow = N - 1;
        #pragma unroll
        for (int c = 0; c < 4; ++c) {
            int k = c * 64 + kg;
            BF8 pk;
            if (k < 128) {
                const float* asrc = s + (size_t)arow * 128 + k;
                float4 f0 = *(const float4*)asrc;
                float4 f1 = *(const float4*)(asrc + 4);
                pk.u[0] = f2bf(f0.x); pk.u[1] = f2bf(f0.y); pk.u[2] = f2bf(f0.z); pk.u[3] = f2bf(f0.w);
                pk.u[4] = f2bf(f1.x); pk.u[5] = f2bf(f1.y); pk.u[6] = f2bf(f1.z); pk.u[7] = f2bf(f1.w);
            } else {
                pk.v = *(const bf16x8*)(GAB + (size_t)arow * 128 + (k - 128));
            }
            *(bf16x8*)&Asub[ar * 264 + k] = pk.v;
        }
    }
    __syncthreads();

    f32x4 acc[2][2];
    #pragma unroll
    for (int i = 0; i < 2; ++i) { acc[i][0] = (f32x4){0,0,0,0}; acc[i][1] = (f32x4){0,0,0,0}; }

    #pragma unroll
    for (int kk = 0; kk < 8; ++kk) {
        bf16x8 b[2];
        #pragma unroll
        for (int ct = 0; ct < 2; ++ct) {
            int g = w * 2 + ct;
            b[ct] = *(const bf16x8*)(WUCF + (size_t)(g * 8 + kk) * 512 + boff);
        }
        bf16x8 a0 = *(const bf16x8*)&Asub[lr * 264 + kk * 32 + lk];
        bf16x8 a1 = *(const bf16x8*)&Asub[(16 + lr) * 264 + kk * 32 + lk];
        #pragma unroll
        for (int ct = 0; ct < 2; ++ct) {
            acc[0][ct] = __builtin_amdgcn_mfma_f32_16x16x32_bf16(a0, b[ct], acc[0][ct], 0, 0, 0);
            acc[1][ct] = __builtin_amdgcn_mfma_f32_16x16x32_bf16(a1, b[ct], acc[1][ct], 0, 0, 0);
        }
    }

    int rbase = lkq * 4;
    #pragma unroll
    for (int ct = 0; ct < 2; ++ct) {
        int col = w * 32 + ct * 16 + lr;
        float b1 = bu1[col], bv = BV[col];
        #pragma unroll
        for (int rt = 0; rt < 2; ++rt) {
            #pragma unroll
            for (int r = 0; r < 4; ++r) {
                int row16 = rt * 16 + rbase + r;
                float v = acc[rt][ct][r] + b1 + SWs[row16] * bv;
                H2[row16 * 136 + col] = (short)f2bf(gelu_fast(v));
            }
        }
    }
    __syncthreads();

    f32x4 acc2[2][2];
    #pragma unroll
    for (int i = 0; i < 2; ++i) { acc2[i][0] = (f32x4){0,0,0,0}; acc2[i][1] = (f32x4){0,0,0,0}; }

    #pragma unroll
    for (int kk = 0; kk < 4; ++kk) {
        bf16x8 b[2];
        #pragma unroll
        for (int ct = 0; ct < 2; ++ct) {
            int g = w * 2 + ct;
            b[ct] = *(const bf16x8*)(WU2F + (size_t)(g * 4 + kk) * 512 + boff);
        }
        bf16x8 a0 = *(const bf16x8*)&H2[lr * 136 + kk * 32 + lk];
        bf16x8 a1 = *(const bf16x8*)&H2[(16 + lr) * 136 + kk * 32 + lk];
        #pragma unroll
        for (int ct = 0; ct < 2; ++ct) {
            acc2[0][ct] = __builtin_amdgcn_mfma_f32_16x16x32_bf16(a0, b[ct], acc2[0][ct], 0, 0, 0);
            acc2[1][ct] = __builtin_amdgcn_mfma_f32_16x16x32_bf16(a1, b[ct], acc2[1][ct], 0, 0, 0);
        }
    }

    #pragma unroll
    for (int ct = 0; ct < 2; ++ct) {
        int col = w * 32 + ct * 16 + lr;
        float b2 = bu2[col];
        #pragma unroll
        for (int rt = 0; rt < 2; ++rt) {
            #pragma unroll
            for (int r = 0; r < 4; ++r) {
                int row = n0 + rt * 16 + rbase + r;
                if (row < N) out[(size_t)row * 128 + col] = acc2[rt][ct][r] + b2;
            }
        }
    }
}

// ---------------------------------------------------------------------------
extern "C" void kernel_launch(void* const* d_in, const int* in_sizes, int n_in,
                              void* d_out, int out_size, void* d_ws, size_t ws_size,
                              hipStream_t stream) {
    const float* s    = (const float*)d_in[0];
    const float* x    = (const float*)d_in[1];
    const int*   ei   = (const int*)d_in[2];
    const float* ew   = (const float*)d_in[3];
    const float* t    = (const float*)d_in[4];
    const float* Wm1  = (const float*)d_in[5];
    const float* bm1  = (const float*)d_in[6];
    const float* Wm2  = (const float*)d_in[7];
    const float* bm2  = (const float*)d_in[8];
    const float* Wu1  = (const float*)d_in[9];
    const float* bu1  = (const float*)d_in[10];
    const float* Wu2  = (const float*)d_in[11];
    const float* bu2  = (const float*)d_in[12];

    int N = in_sizes[0] / 128;
    int E = in_sizes[2] / 2;
    const int* srcI = ei;
    const int* dstI = ei + E;
    int NP = (N + CHUNK - 1) & ~(CHUNK - 1);
    int C  = NP / CHUNK;

    // workspace layout (32-bit words)
    float* ws = (float*)d_ws;
    size_t off = 0;
    ushort* Pb   = (ushort*)(ws + off); off += (size_t)N * 64;
    ushort* Qb   = (ushort*)(ws + off); off += (size_t)N * 64;
    float*  SW   = ws + off; off += ((size_t)N + 63) & ~(size_t)63;
    ushort* GAB  = (ushort*)(ws + off); off += (size_t)N * 64;
    ushort* WC1F = (ushort*)(ws + off); off += (256 * 320) / 2;
    ushort* WUCF = (ushort*)(ws + off); off += (128 * 256) / 2;
    ushort* WU2F = (ushort*)(ws + off); off += (128 * 128) / 2;
    float*  BV   = ws + off; off += 128;
    int*    DEG  = (int*)(ws + off); off += (size_t)NP;
    int*    OFFS = (int*)(ws + off); off += (size_t)NP + 64;
    off = (off + 3) & ~(size_t)3;
    int*    CUR  = (int*)(ws + off); off += (size_t)NP;
    int*    CSUM = (int*)(ws + off); off += 128;
    int*    CBASE= (int*)(ws + off); off += 128;
    off = (off + 3) & ~(size_t)3;
    int2*   REC  = (int2*)(ws + off); off += (size_t)E * 2;

    // zero histogram, then fused weight-prep + histogram
    hipMemsetAsync(DEG, 0, (size_t)NP * sizeof(int), stream);
    int histBlocks = (E + 255) / 256;
    k_prep<<<512 + histBlocks, 256, 0, stream>>>(Wm1, Wu1, Wm2, bm2, Wu2, dstI, E,
                                                 WC1F, WUCF, WU2F, BV, DEG);

    // counting sort tail
    k_chunksum<<<C, 256, 0, stream>>>(DEG, CSUM);
    k_chunkscan<<<1, 64, 0, stream>>>(CSUM, CBASE, C, OFFS, N, E);
    k_chunkoffs<<<C, 256, 0, stream>>>(DEG, CBASE, OFFS, CUR);
    k_scatter<<<(E + 255) / 256, 256, 0, stream>>>(srcI, dstI, ew, CUR, REC, E);

    // node precompute (MFMA)
    int nb32 = (N + 31) / 32;
    k1_mfma<<<nb32, 256, 0, stream>>>(s, x, t, WC1F, bm1, Pb, Qb, N);

    // segmented aggregation (scalar gelu, pipelined gathers)
    k_agg<<<(N + 3) / 4, 256, 0, stream>>>(Pb, Qb, REC, OFFS, GAB, SW, N);

    // update MLP (MFMA, fused)
    k3_mfma<<<nb32, 256, 0, stream>>>(s, GAB, SW, WUCF, BV, bu1, WU2F, bu2, (float*)d_out, N);
}